// Round 9
// baseline (189.885 us; speedup 1.0000x reference)
//
#include <hip/hip_runtime.h>

typedef __bf16 bf16x8 __attribute__((ext_vector_type(8)));
typedef short short8 __attribute__((ext_vector_type(8)));
typedef float f32x4 __attribute__((ext_vector_type(4)));

// B=8, T=2048, E=512, H=8, d=64
#define TT 2048
#define EE 512
#define NH 8
#define DD 64

#define QSCALE 0.36067376022224085f   // 0.25 * log2(e)
#define CSCALE 0.18033688011112042f   // 0.125 * log2(e)

__device__ __forceinline__ ushort f2bf(float f) {
  union { float f; unsigned u; } a; a.f = f;
  unsigned u = a.u;
  return (ushort)((u + 0x7FFFu + ((u >> 16) & 1u)) >> 16);  // RNE
}

// ---------------- Kernel 1: LayerNorm + Q',K scalars + xn (bf16) -----------
// wave per token; 256 threads = 4 tokens/block; grid = 4096
__global__ __launch_bounds__(256) void k_ln(
    const float* __restrict__ x, const float* __restrict__ Wq,
    const float* __restrict__ Wk,
    float* __restrict__ Q, float* __restrict__ K, ushort* __restrict__ xnb) {
  const int token = blockIdx.x * 4 + (threadIdx.x >> 6);
  const int l = threadIdx.x & 63;
  const float* xr = x + (size_t)token * EE + l * 8;
  float4 a = *(const float4*)xr;
  float4 c = *(const float4*)(xr + 4);
  float xv[8] = {a.x, a.y, a.z, a.w, c.x, c.y, c.z, c.w};
  float s = 0.f, s2 = 0.f;
#pragma unroll
  for (int i = 0; i < 8; i++) { s += xv[i]; s2 = fmaf(xv[i], xv[i], s2); }
#pragma unroll
  for (int o = 32; o; o >>= 1) { s += __shfl_xor(s, o); s2 += __shfl_xor(s2, o); }
  const float mean = s * (1.f / 512.f);
  const float var = s2 * (1.f / 512.f) - mean * mean;
  const float rstd = rsqrtf(var + 1e-5f);

  float xn[8];
  short8 ob;
#pragma unroll
  for (int i = 0; i < 8; i++) {
    xn[i] = (xv[i] - mean) * rstd;
    ob[i] = (short)f2bf(xn[i]);
  }
  *(short8*)(xnb + (size_t)token * EE + l * 8) = ob;

  const float* wq = Wq + l * 8;
  const float* wk = Wk + l * 8;
  float4 q1 = *(const float4*)wq, q2 = *(const float4*)(wq + 4);
  float4 k1 = *(const float4*)wk, k2 = *(const float4*)(wk + 4);
  float wqv[8] = {q1.x, q1.y, q1.z, q1.w, q2.x, q2.y, q2.z, q2.w};
  float wkv[8] = {k1.x, k1.y, k1.z, k1.w, k2.x, k2.y, k2.z, k2.w};
  float q = 0.f, k = 0.f;
#pragma unroll
  for (int i = 0; i < 8; i++) { q = fmaf(xn[i], wqv[i], q); k = fmaf(xn[i], wkv[i], k); }
#pragma unroll
  for (int o = 4; o; o >>= 1) { q += __shfl_xor(q, o); k += __shfl_xor(k, o); }
  if ((l & 7) == 0) {
    const int h = l >> 3;
    const int b = token >> 11, t = token & (TT - 1);
    const int bh = b * NH + h;
    Q[bh * TT + t] = q * QSCALE;
    K[bh * TT + t] = k;
  }
}

// ---------------- Kernel 1b: transpose xnb -> xnt[bh][e][t] (LINEAR) -------
__global__ __launch_bounds__(256) void k_tr(const ushort* __restrict__ xnb,
                                            ushort* __restrict__ xnt) {
  const int bh = blockIdx.y;
  const int b = bh >> 3, h = bh & 7;
  const int t0 = blockIdx.x * 64;
  const int tid = threadIdx.x;
  __shared__ ushort tile[64][72];

  {
    const int i = tid >> 3, ec = (tid & 7) * 8;
    const ushort* src = xnb + (size_t)(b * TT + t0 + i) * EE + h * DD + ec;
    *(uint4*)&tile[i][ec] = *(const uint4*)src;
    *(uint4*)&tile[i + 32][ec] = *(const uint4*)(src + 32 * EE);
  }
  __syncthreads();
  {
    const int e = tid >> 3, tc = (tid & 7) * 8;
    union { uint4 v; ushort u[8]; } o0, o1;
#pragma unroll
    for (int i = 0; i < 8; i++) {
      o0.u[i] = tile[tc + i][e];
      o1.u[i] = tile[tc + i][e + 32];
    }
    ushort* dst = xnt + (size_t)(bh * DD + e) * TT + t0 + tc;
    *(uint4*)dst = o0.v;
    *(uint4*)(dst + (size_t)32 * TT) = o1.v;
  }
}

// ---------------- Kernel 2: Wvmt[n][k] = (Wv_h @ Wm_h)^T, bf16 -------------
// block per k (512 blocks); Wm rows read coalesced across 256 threads
__global__ __launch_bounds__(256) void k_wvm(
    const float* __restrict__ Wv, const float* __restrict__ Wm,
    ushort* __restrict__ Wvmt) {
  const int k = blockIdx.x;
  const int h = k >> 6;
  const int tid = threadIdx.x;
  __shared__ float wv[64];
  if (tid < 64) wv[tid] = Wv[k * 64 + tid];
  __syncthreads();
  float a0 = 0.f, a1 = 0.f;
#pragma unroll 8
  for (int e = 0; e < 64; e++) {
    const float w = wv[e];
    const float* row = Wm + (size_t)(h * 64 + e) * EE;
    a0 = fmaf(w, row[tid], a0);
    a1 = fmaf(w, row[tid + 256], a1);
  }
  Wvmt[(size_t)tid * EE + k] = f2bf(a0);
  Wvmt[(size_t)(tid + 256) * EE + k] = f2bf(a1);
}

// ---------------- Kernel 3: distance attention, G = P @ XN_h ---------------
// grid = 1024 (XCD-swizzled, 64bh x 16 q-chunks of 128); 256 thr = 4 waves
// F=2 (32 q-rows/wave) -> 4096 waves = 4/SIMD. NO per-tile barriers, NO vt
// staging: vf fragments read DIRECT from L2-resident linear xnt; the exp
// phase (ks/cs-only deps) covers the vf load latency. ks/cs in LDS.
__global__ __launch_bounds__(256, 4) void k_attn(
    const float* __restrict__ Q, const float* __restrict__ K,
    const ushort* __restrict__ xnt, ushort* __restrict__ hr) {
  const int sw = (blockIdx.x & 7) * 128 + (blockIdx.x >> 3);  // bijective XCD swizzle
  const int bh = sw >> 4;
  const int q0 = (sw & 15) * 128;
  const int b = bh >> 3, h = bh & 7;
  const int tid = threadIdx.x;
  const int w = tid >> 6, l = tid & 63;
  const int l16 = l & 15, lhi = l >> 4;

  __shared__ float ks[TT];
  __shared__ float cs[TT];

  {
    const float* Kb = K + bh * TT;
#pragma unroll
    for (int i = 0; i < 8; i++) {
      float kv = Kb[tid + i * 256];
      ks[tid + i * 256] = kv;
      cs[tid + i * 256] = -kv * kv * CSCALE;
    }
  }
  __syncthreads();

  float qv[2];
  qv[0] = Q[bh * TT + q0 + w * 32 + l16];
  qv[1] = Q[bh * TT + q0 + w * 32 + 16 + l16];

  f32x4 acc[2][4];
  f32x4 accd[2];
#pragma unroll
  for (int f = 0; f < 2; f++) {
    accd[f] = (f32x4){0.f, 0.f, 0.f, 0.f};
#pragma unroll
    for (int c = 0; c < 4; c++) acc[f][c] = (f32x4){0.f, 0.f, 0.f, 0.f};
  }
  short8 onesbits = {0x3F80, 0x3F80, 0x3F80, 0x3F80, 0x3F80, 0x3F80, 0x3F80, 0x3F80};
  const bf16x8 ones = __builtin_bit_cast(bf16x8, onesbits);

  // fragment source: row e = c*16 + l16, j = jt + kk*32 + lhi*8
  const ushort* Xt = xnt + (size_t)bh * (DD * TT) + (size_t)l16 * TT;
  const int jo = lhi * 8;

  for (int jt = 0; jt < TT; jt += 64) {
    // issue all 8 vf loads first (L2 hits; latency hidden under exp phase)
    bf16x8 vf0[4], vf1[4];
#pragma unroll
    for (int c = 0; c < 4; c++) {
      const ushort* base = Xt + (size_t)c * 16 * TT + jt + jo;
      vf0[c] = *(const bf16x8*)(base);
      vf1[c] = *(const bf16x8*)(base + 32);
    }

    // exp phase: depends only on LDS ks/cs (fast), not on vf
    bf16x8 pa[2][2];
#pragma unroll
    for (int kk = 0; kk < 2; kk++) {
      const int jb = jt + kk * 32 + jo;
      float4 ka = *(const float4*)&ks[jb];
      float4 kb2 = *(const float4*)&ks[jb + 4];
      float4 ca = *(const float4*)&cs[jb];
      float4 cb2 = *(const float4*)&cs[jb + 4];
      float kv8[8] = {ka.x, ka.y, ka.z, ka.w, kb2.x, kb2.y, kb2.z, kb2.w};
      float cv8[8] = {ca.x, ca.y, ca.z, ca.w, cb2.x, cb2.y, cb2.z, cb2.w};
#pragma unroll
      for (int f = 0; f < 2; f++) {
#pragma unroll
        for (int i = 0; i < 8; i++)
          pa[kk][f][i] = (__bf16)__builtin_amdgcn_exp2f(fmaf(qv[f], kv8[i], cv8[i]));
      }
    }

    // MFMA phase: consumes vf (loads complete by now)
    __builtin_amdgcn_s_setprio(1);
#pragma unroll
    for (int kk = 0; kk < 2; kk++) {
#pragma unroll
      for (int f = 0; f < 2; f++) {
        accd[f] = __builtin_amdgcn_mfma_f32_16x16x32_bf16(pa[kk][f], ones, accd[f], 0, 0, 0);
#pragma unroll
        for (int c = 0; c < 4; c++)
          acc[f][c] = __builtin_amdgcn_mfma_f32_16x16x32_bf16(
              pa[kk][f], kk ? vf1[c] : vf0[c], acc[f][c], 0, 0, 0);
      }
    }
    __builtin_amdgcn_s_setprio(0);
  }

#pragma unroll
  for (int f = 0; f < 2; f++) {
#pragma unroll
    for (int r = 0; r < 4; r++) {
      // C/D layout: row = lhi*4 + r, col = l16; accd row-sum is col-invariant
      const float rinv = 1.f / accd[f][r];
      const int qrow = q0 + w * 32 + f * 16 + lhi * 4 + r;
      const size_t base = ((size_t)(b * TT + qrow)) * EE + h * DD + l16;
#pragma unroll
      for (int c = 0; c < 4; c++)
        hr[base + c * 16] = f2bf(acc[f][c][r] * rinv);
    }
  }
}

// ---------------- Kernel 4: out = hr @ Wvm + x  (bf16 MFMA GEMM) -----------
// grid = (4, 128); 256 threads (4 waves, 2x2 wave grid, 64x64 each)
// XCD-grouped remap: each XCD owns 16 m-tiles, all 4 n-blocks -> hr L2 reuse
__global__ __launch_bounds__(256, 2) void k_merge(
    const ushort* __restrict__ hr, const ushort* __restrict__ Wmt,
    const float* __restrict__ x, float* __restrict__ out) {
  const int fid = blockIdx.y * 4 + blockIdx.x;   // dispatch order (x fastest)
  const int xcd = fid & 7, idx = fid >> 3;
  const int n0 = (idx & 3) * 128;
  const int m0 = (xcd * 16 + (idx >> 2)) * 128;
  const int tid = threadIdx.x;
  const int w = tid >> 6, l = tid & 63;
  const int l16 = l & 15, lhi = l >> 4;
  const int wm = w >> 1, wn = w & 1;

  __shared__ ushort As[2][128 * 72];
  __shared__ ushort Bs[2][128 * 72];
  f32x4 acc[4][4];
#pragma unroll
  for (int i = 0; i < 4; i++)
#pragma unroll
    for (int j = 0; j < 4; j++) acc[i][j] = (f32x4){0.f, 0.f, 0.f, 0.f};

  const int row = tid >> 1, half = tid & 1;
  const ushort* sa0 = hr + (size_t)(m0 + row) * EE + half * 32;
  const ushort* sb0 = Wmt + (size_t)(n0 + row) * EE + half * 32;

  // prologue: stage k-step 0
  {
    uint4* da = (uint4*)&As[0][row * 72 + half * 32];
    uint4* db = (uint4*)&Bs[0][row * 72 + half * 32];
#pragma unroll
    for (int i = 0; i < 4; i++) da[i] = *(const uint4*)(sa0 + i * 8);
#pragma unroll
    for (int i = 0; i < 4; i++) db[i] = *(const uint4*)(sb0 + i * 8);
  }
  __syncthreads();

  int p = 0;
  for (int k0 = 0; k0 < EE; k0 += 64) {
    const bool more = (k0 + 64) < EE;
    uint4 pa[4], pb[4];
    if (more) {
#pragma unroll
      for (int i = 0; i < 4; i++) pa[i] = *(const uint4*)(sa0 + k0 + 64 + i * 8);
#pragma unroll
      for (int i = 0; i < 4; i++) pb[i] = *(const uint4*)(sb0 + k0 + 64 + i * 8);
    }
#pragma unroll
    for (int kk = 0; kk < 2; kk++) {
      bf16x8 af[4], bfr[4];
#pragma unroll
      for (int mi = 0; mi < 4; mi++)
        af[mi] = *(const bf16x8*)&As[p][(wm * 64 + mi * 16 + l16) * 72 + kk * 32 + lhi * 8];
#pragma unroll
      for (int ni = 0; ni < 4; ni++)
        bfr[ni] = *(const bf16x8*)&Bs[p][(wn * 64 + ni * 16 + l16) * 72 + kk * 32 + lhi * 8];
#pragma unroll
      for (int mi = 0; mi < 4; mi++)
#pragma unroll
        for (int ni = 0; ni < 4; ni++)
          acc[mi][ni] = __builtin_amdgcn_mfma_f32_16x16x32_bf16(af[mi], bfr[ni], acc[mi][ni], 0, 0, 0);
    }
    if (more) {
      uint4* da = (uint4*)&As[p ^ 1][row * 72 + half * 32];
      uint4* db = (uint4*)&Bs[p ^ 1][row * 72 + half * 32];
#pragma unroll
      for (int i = 0; i < 4; i++) da[i] = pa[i];
#pragma unroll
      for (int i = 0; i < 4; i++) db[i] = pb[i];
    }
    __syncthreads();
    p ^= 1;
  }

#pragma unroll
  for (int mi = 0; mi < 4; mi++) {
#pragma unroll
    for (int r = 0; r < 4; r++) {
      const int grow = m0 + wm * 64 + mi * 16 + lhi * 4 + r;
#pragma unroll
      for (int ni = 0; ni < 4; ni++) {
        const int gcol = n0 + wn * 64 + ni * 16 + l16;
        size_t idx2 = (size_t)grow * EE + gcol;
        out[idx2] = acc[mi][ni][r] + x[idx2];
      }
    }
  }
}

// ---------------- launch ----------------------------------------------------
extern "C" void kernel_launch(void* const* d_in, const int* in_sizes, int n_in,
                              void* d_out, int out_size, void* d_ws, size_t ws_size,
                              hipStream_t stream) {
  const float* x  = (const float*)d_in[0];
  const float* Wq = (const float*)d_in[1];
  const float* Wk = (const float*)d_in[2];
  const float* Wv = (const float*)d_in[3];
  const float* Wm = (const float*)d_in[4];
  float* out = (float*)d_out;

  char* ws = (char*)d_ws;
  // layout: Q' f32 | K f32 | xnb bf16 (dead after k_tr; hr overlays it) |
  //         xnt bf16 [64bh][64e][2048t] LINEAR | Wvmt bf16
  float*  Qp   = (float*)(ws);
  float*  Kp   = (float*)(ws + 524288);
  ushort* xnb  = (ushort*)(ws + 1048576);
  ushort* hrp  = (ushort*)(ws + 1048576);   // overlays xnb (dead after k_tr)
  ushort* xnt  = (ushort*)(ws + 17825792);
  ushort* Wvmt = (ushort*)(ws + 34603008);

  k_ln<<<4096, 256, 0, stream>>>(x, Wq, Wk, Qp, Kp, xnb);
  k_tr<<<dim3(TT / 64, 8 * NH), 256, 0, stream>>>(xnb, xnt);
  k_wvm<<<EE, 256, 0, stream>>>(Wv, Wm, Wvmt);
  k_attn<<<1024, 256, 0, stream>>>(Qp, Kp, xnt, hrp);
  k_merge<<<dim3(EE / 128, (8 * TT) / 128), 256, 0, stream>>>(hrp, Wvmt, x, out);
}

// Round 10
// 142.306 us; speedup vs baseline: 1.3343x; 1.3343x over previous
//
#include <hip/hip_runtime.h>

typedef __bf16 bf16x8 __attribute__((ext_vector_type(8)));
typedef short short8 __attribute__((ext_vector_type(8)));
typedef float f32x4 __attribute__((ext_vector_type(4)));

// B=8, T=2048, E=512, H=8, d=64
#define TT 2048
#define EE 512
#define NH 8
#define DD 64

#define QSCALE 0.36067376022224085f   // 0.25 * log2(e)
#define CSCALE 0.18033688011112042f   // 0.125 * log2(e)

__device__ __forceinline__ ushort f2bf(float f) {
  union { float f; unsigned u; } a; a.f = f;
  unsigned u = a.u;
  return (ushort)((u + 0x7FFFu + ((u >> 16) & 1u)) >> 16);  // RNE
}

// ---------------- Kernel 1: LayerNorm + Q',K scalars + xn (bf16) -----------
// wave per token; 256 threads = 4 tokens/block; grid = 4096
__global__ __launch_bounds__(256) void k_ln(
    const float* __restrict__ x, const float* __restrict__ Wq,
    const float* __restrict__ Wk,
    float* __restrict__ Q, float* __restrict__ K, ushort* __restrict__ xnb) {
  const int token = blockIdx.x * 4 + (threadIdx.x >> 6);
  const int l = threadIdx.x & 63;
  const float* xr = x + (size_t)token * EE + l * 8;
  float4 a = *(const float4*)xr;
  float4 c = *(const float4*)(xr + 4);
  float xv[8] = {a.x, a.y, a.z, a.w, c.x, c.y, c.z, c.w};
  float s = 0.f, s2 = 0.f;
#pragma unroll
  for (int i = 0; i < 8; i++) { s += xv[i]; s2 = fmaf(xv[i], xv[i], s2); }
#pragma unroll
  for (int o = 32; o; o >>= 1) { s += __shfl_xor(s, o); s2 += __shfl_xor(s2, o); }
  const float mean = s * (1.f / 512.f);
  const float var = s2 * (1.f / 512.f) - mean * mean;
  const float rstd = rsqrtf(var + 1e-5f);

  float xn[8];
  short8 ob;
#pragma unroll
  for (int i = 0; i < 8; i++) {
    xn[i] = (xv[i] - mean) * rstd;
    ob[i] = (short)f2bf(xn[i]);
  }
  *(short8*)(xnb + (size_t)token * EE + l * 8) = ob;

  const float* wq = Wq + l * 8;
  const float* wk = Wk + l * 8;
  float4 q1 = *(const float4*)wq, q2 = *(const float4*)(wq + 4);
  float4 k1 = *(const float4*)wk, k2 = *(const float4*)(wk + 4);
  float wqv[8] = {q1.x, q1.y, q1.z, q1.w, q2.x, q2.y, q2.z, q2.w};
  float wkv[8] = {k1.x, k1.y, k1.z, k1.w, k2.x, k2.y, k2.z, k2.w};
  float q = 0.f, k = 0.f;
#pragma unroll
  for (int i = 0; i < 8; i++) { q = fmaf(xn[i], wqv[i], q); k = fmaf(xn[i], wkv[i], k); }
#pragma unroll
  for (int o = 4; o; o >>= 1) { q += __shfl_xor(q, o); k += __shfl_xor(k, o); }
  if ((l & 7) == 0) {
    const int h = l >> 3;
    const int b = token >> 11, t = token & (TT - 1);
    const int bh = b * NH + h;
    Q[bh * TT + t] = q * QSCALE;
    K[bh * TT + t] = k;
  }
}

// ---------------- Kernel 1b: transpose xnb -> xnt[bh][e][t], PRE-SWIZZLED --
// within each 64-j block, 8-j chunk c of row e stored at chunk (c ^ (e&7))
__global__ __launch_bounds__(256) void k_tr(const ushort* __restrict__ xnb,
                                            ushort* __restrict__ xnt) {
  const int bh = blockIdx.y;
  const int b = bh >> 3, h = bh & 7;
  const int t0 = blockIdx.x * 64;
  const int tid = threadIdx.x;
  __shared__ ushort tile[64][72];

  {
    const int i = tid >> 3, ec = (tid & 7) * 8;
    const ushort* src = xnb + (size_t)(b * TT + t0 + i) * EE + h * DD + ec;
    *(uint4*)&tile[i][ec] = *(const uint4*)src;
    *(uint4*)&tile[i + 32][ec] = *(const uint4*)(src + 32 * EE);
  }
  __syncthreads();
  {
    const int e = tid >> 3, chunk = tid & 7, tc = (tid & 7) * 8;
    union { uint4 v; ushort u[8]; } o0, o1;
#pragma unroll
    for (int i = 0; i < 8; i++) {
      o0.u[i] = tile[tc + i][e];
      o1.u[i] = tile[tc + i][e + 32];
    }
    const int soff = ((chunk ^ (e & 7)) << 3);  // same key for e and e+32
    ushort* dst = xnt + (size_t)(bh * DD + e) * TT + t0 + soff;
    *(uint4*)dst = o0.v;
    *(uint4*)(dst + (size_t)32 * TT) = o1.v;
  }
}

// ---------------- Kernel 2: Wvmt[n][k] = (Wv_h @ Wm_h)^T, bf16 -------------
// block per k (512 blocks); Wm rows read coalesced across 256 threads
__global__ __launch_bounds__(256) void k_wvm(
    const float* __restrict__ Wv, const float* __restrict__ Wm,
    ushort* __restrict__ Wvmt) {
  const int k = blockIdx.x;
  const int h = k >> 6;
  const int tid = threadIdx.x;
  __shared__ float wv[64];
  if (tid < 64) wv[tid] = Wv[k * 64 + tid];
  __syncthreads();
  float a0 = 0.f, a1 = 0.f;
#pragma unroll 8
  for (int e = 0; e < 64; e++) {
    const float w = wv[e];
    const float* row = Wm + (size_t)(h * 64 + e) * EE;
    a0 = fmaf(w, row[tid], a0);
    a1 = fmaf(w, row[tid + 256], a1);
  }
  Wvmt[(size_t)tid * EE + k] = f2bf(a0);
  Wvmt[(size_t)(tid + 256) * EE + k] = f2bf(a1);
}

// ---------------- Kernel 3: distance attention, G = P @ XN_h ---------------
// grid = 512 (XCD-swizzled); 256 threads = 4 waves; F=4 (64 q-rows/wave)
// 4-tile barrier periods: vt dbuf 2x4x(64x64), 8 barriers total; inside a
// period tiles pipeline freely (no sync). cs recomputed from ks (VALU).
__global__ __launch_bounds__(256, 2) void k_attn(
    const float* __restrict__ Q, const float* __restrict__ K,
    const ushort* __restrict__ xnt, ushort* __restrict__ hr) {
  const int sw = (blockIdx.x & 7) * 64 + (blockIdx.x >> 3);  // bijective XCD swizzle
  const int bh = sw >> 3;
  const int q0 = (sw & 7) * 256;
  const int b = bh >> 3, h = bh & 7;
  const int tid = threadIdx.x;
  const int w = tid >> 6, l = tid & 63;
  const int l16 = l & 15, lhi = l >> 4;

  __shared__ float ks[TT];
  __shared__ ushort vt[2][4][64 * 64];   // 64 KB

  {
    const float* Kb = K + bh * TT;
#pragma unroll
    for (int i = 0; i < 8; i++) ks[tid + i * 256] = Kb[tid + i * 256];
  }

  // staging geometry: lane -> rows e = tid>>3 and +32, chunk tid&7 (16B)
  const ushort* Xs = xnt + (size_t)bh * (DD * TT);
  const int se = tid >> 3;           // 0..31
  const int sc = (tid & 7) * 8;      // ushort offset within 64-j row
  uint4 stA[4], stB[4];

#define ISSUE(st, jp_) do {                                                    \
    st[0] = *(const uint4*)(Xs + (size_t)se * TT + (jp_) + sc);                \
    st[1] = *(const uint4*)(Xs + (size_t)(se + 32) * TT + (jp_) + sc);         \
    st[2] = *(const uint4*)(Xs + (size_t)se * TT + (jp_) + 64 + sc);           \
    st[3] = *(const uint4*)(Xs + (size_t)(se + 32) * TT + (jp_) + 64 + sc);    \
  } while (0)

#define WRITEST(st, buf_, t0_) do {                                            \
    *(uint4*)&vt[buf_][t0_][se * 64 + sc] = st[0];                             \
    *(uint4*)&vt[buf_][t0_][(se + 32) * 64 + sc] = st[1];                      \
    *(uint4*)&vt[buf_][(t0_) + 1][se * 64 + sc] = st[2];                       \
    *(uint4*)&vt[buf_][(t0_) + 1][(se + 32) * 64 + sc] = st[3];                \
  } while (0)

  // prologue: stage period 0 (4 tiles)
  ISSUE(stA, 0);   WRITEST(stA, 0, 0);
  ISSUE(stB, 128); WRITEST(stB, 0, 2);
  __syncthreads();

  float qv[4];
#pragma unroll
  for (int f = 0; f < 4; f++) qv[f] = Q[bh * TT + q0 + w * 64 + f * 16 + l16];

  f32x4 acc[4][4];
  f32x4 accd[4];
#pragma unroll
  for (int f = 0; f < 4; f++) {
    accd[f] = (f32x4){0.f, 0.f, 0.f, 0.f};
#pragma unroll
    for (int c = 0; c < 4; c++) acc[f][c] = (f32x4){0.f, 0.f, 0.f, 0.f};
  }
  short8 onesbits = {0x3F80, 0x3F80, 0x3F80, 0x3F80, 0x3F80, 0x3F80, 0x3F80, 0x3F80};
  const bf16x8 ones = __builtin_bit_cast(bf16x8, onesbits);

#define TILE(cur_, tt_, jt_) do {                                              \
    _Pragma("unroll") for (int kk = 0; kk < 2; kk++) {                         \
      bf16x8 vf[4];                                                            \
      _Pragma("unroll") for (int c = 0; c < 4; c++) {                          \
        const int e = c * 16 + l16;                                            \
        vf[c] = *(const bf16x8*)&vt[cur_][tt_][e * 64 +                        \
                    (((kk * 4 + lhi) ^ (e & 7)) << 3)];                        \
      }                                                                        \
      const int jb = (jt_) + kk * 32 + lhi * 8;                                \
      float4 ka = *(const float4*)&ks[jb];                                     \
      float4 kb2 = *(const float4*)&ks[jb + 4];                                \
      float kv8[8] = {ka.x, ka.y, ka.z, ka.w, kb2.x, kb2.y, kb2.z, kb2.w};     \
      float cv8[8];                                                            \
      _Pragma("unroll") for (int i = 0; i < 8; i++) {                          \
        float m = kv8[i] * (-CSCALE);                                          \
        cv8[i] = m * kv8[i];                                                   \
      }                                                                        \
      _Pragma("unroll") for (int f = 0; f < 4; f++) {                          \
        bf16x8 pa;                                                             \
        _Pragma("unroll") for (int i = 0; i < 8; i++)                          \
          pa[i] = (__bf16)__builtin_amdgcn_exp2f(fmaf(qv[f], kv8[i], cv8[i])); \
        accd[f] = __builtin_amdgcn_mfma_f32_16x16x32_bf16(pa, ones, accd[f], 0, 0, 0); \
        _Pragma("unroll") for (int c = 0; c < 4; c++)                          \
          acc[f][c] = __builtin_amdgcn_mfma_f32_16x16x32_bf16(pa, vf[c], acc[f][c], 0, 0, 0); \
      }                                                                        \
    }                                                                          \
  } while (0)

  int cur = 0;
  for (int pp = 0; pp < 8; pp++) {
    const int jp = pp * 256;
    const bool more = pp < 7;
    if (more) ISSUE(stA, jp + 256);          // issue-early pair 1
    __builtin_amdgcn_s_setprio(1);
    TILE(cur, 0, jp);
    TILE(cur, 1, jp + 64);
    __builtin_amdgcn_s_setprio(0);
    if (more) {
      WRITEST(stA, cur ^ 1, 0);              // write-late pair 1
      ISSUE(stB, jp + 256 + 128);            // issue-early pair 2
    }
    __builtin_amdgcn_s_setprio(1);
    TILE(cur, 2, jp + 128);
    TILE(cur, 3, jp + 192);
    __builtin_amdgcn_s_setprio(0);
    if (more) WRITEST(stB, cur ^ 1, 2);      // write-late pair 2
    __syncthreads();
    cur ^= 1;
  }
#undef ISSUE
#undef WRITEST
#undef TILE

#pragma unroll
  for (int f = 0; f < 4; f++) {
#pragma unroll
    for (int r = 0; r < 4; r++) {
      // C/D layout: row = lhi*4 + r, col = l16; accd row-sum is col-invariant
      const float rinv = 1.f / accd[f][r];
      const int qrow = q0 + w * 64 + f * 16 + lhi * 4 + r;
      const size_t base = ((size_t)(b * TT + qrow)) * EE + h * DD + l16;
#pragma unroll
      for (int c = 0; c < 4; c++)
        hr[base + c * 16] = f2bf(acc[f][c][r] * rinv);
    }
  }
}

// ---------------- Kernel 4: out = hr @ Wvm + x  (bf16 MFMA GEMM) -----------
// grid = (4, 128); 256 threads (4 waves, 2x2 wave grid, 64x64 each)
// XCD-grouped remap for hr L2 reuse; LDS-transposed coalesced epilogue.
__global__ __launch_bounds__(256, 2) void k_merge(
    const ushort* __restrict__ hr, const ushort* __restrict__ Wmt,
    const float* __restrict__ x, float* __restrict__ out) {
  const int fid = blockIdx.y * 4 + blockIdx.x;   // dispatch order (x fastest)
  const int xcd = fid & 7, idx = fid >> 3;
  const int n0 = (idx & 3) * 128;
  const int m0 = (xcd * 16 + (idx >> 2)) * 128;
  const int tid = threadIdx.x;
  const int w = tid >> 6, l = tid & 63;
  const int l16 = l & 15, lhi = l >> 4;
  const int wm = w >> 1, wn = w & 1;

  __shared__ ushort smem[36864];               // As[2]|Bs[2] staging; f32 epi reuse
#define AS(p) (smem + (p) * 9216)
#define BS(p) (smem + 18432 + (p) * 9216)

  f32x4 acc[4][4];
#pragma unroll
  for (int i = 0; i < 4; i++)
#pragma unroll
    for (int j = 0; j < 4; j++) acc[i][j] = (f32x4){0.f, 0.f, 0.f, 0.f};

  const int row = tid >> 1, half = tid & 1;
  const ushort* sa0 = hr + (size_t)(m0 + row) * EE + half * 32;
  const ushort* sb0 = Wmt + (size_t)(n0 + row) * EE + half * 32;

  // prologue: stage k-step 0
  {
    uint4* da = (uint4*)&AS(0)[row * 72 + half * 32];
    uint4* db = (uint4*)&BS(0)[row * 72 + half * 32];
#pragma unroll
    for (int i = 0; i < 4; i++) da[i] = *(const uint4*)(sa0 + i * 8);
#pragma unroll
    for (int i = 0; i < 4; i++) db[i] = *(const uint4*)(sb0 + i * 8);
  }
  __syncthreads();

  int p = 0;
  for (int k0 = 0; k0 < EE; k0 += 64) {
    const bool more = (k0 + 64) < EE;
    uint4 pa[4], pb[4];
    if (more) {
#pragma unroll
      for (int i = 0; i < 4; i++) pa[i] = *(const uint4*)(sa0 + k0 + 64 + i * 8);
#pragma unroll
      for (int i = 0; i < 4; i++) pb[i] = *(const uint4*)(sb0 + k0 + 64 + i * 8);
    }
#pragma unroll
    for (int kk = 0; kk < 2; kk++) {
      bf16x8 af[4], bfr[4];
#pragma unroll
      for (int mi = 0; mi < 4; mi++)
        af[mi] = *(const bf16x8*)&AS(p)[(wm * 64 + mi * 16 + l16) * 72 + kk * 32 + lhi * 8];
#pragma unroll
      for (int ni = 0; ni < 4; ni++)
        bfr[ni] = *(const bf16x8*)&BS(p)[(wn * 64 + ni * 16 + l16) * 72 + kk * 32 + lhi * 8];
#pragma unroll
      for (int mi = 0; mi < 4; mi++)
#pragma unroll
        for (int ni = 0; ni < 4; ni++)
          acc[mi][ni] = __builtin_amdgcn_mfma_f32_16x16x32_bf16(af[mi], bfr[ni], acc[mi][ni], 0, 0, 0);
    }
    if (more) {
      uint4* da = (uint4*)&AS(p ^ 1)[row * 72 + half * 32];
      uint4* db = (uint4*)&BS(p ^ 1)[row * 72 + half * 32];
#pragma unroll
      for (int i = 0; i < 4; i++) da[i] = pa[i];
#pragma unroll
      for (int i = 0; i < 4; i++) db[i] = pb[i];
    }
    __syncthreads();
    p ^= 1;
  }

  // epilogue: acc -> LDS f32[128][132] -> coalesced float4 stores (+residual)
  float* ldsf = (float*)smem;
#pragma unroll
  for (int mi = 0; mi < 4; mi++) {
#pragma unroll
    for (int r = 0; r < 4; r++) {
      const int orow = wm * 64 + mi * 16 + lhi * 4 + r;
#pragma unroll
      for (int ni = 0; ni < 4; ni++)
        ldsf[orow * 132 + wn * 64 + ni * 16 + l16] = acc[mi][ni][r];
    }
  }
  __syncthreads();
  {
    const int orow = tid >> 1, cb = (tid & 1) * 64;
    const int grow = m0 + orow;
    const float* xr = x + (size_t)grow * EE + n0 + cb;
    float* og = out + (size_t)grow * EE + n0 + cb;
    const float* lr = ldsf + orow * 132 + cb;
#pragma unroll
    for (int i = 0; i < 16; i++) {
      float4 xa = *(const float4*)(xr + i * 4);
      float4 v = *(const float4*)(lr + i * 4);
      v.x += xa.x; v.y += xa.y; v.z += xa.z; v.w += xa.w;
      *(float4*)(og + i * 4) = v;
    }
  }
#undef AS
#undef BS
}

// ---------------- launch ----------------------------------------------------
extern "C" void kernel_launch(void* const* d_in, const int* in_sizes, int n_in,
                              void* d_out, int out_size, void* d_ws, size_t ws_size,
                              hipStream_t stream) {
  const float* x  = (const float*)d_in[0];
  const float* Wq = (const float*)d_in[1];
  const float* Wk = (const float*)d_in[2];
  const float* Wv = (const float*)d_in[3];
  const float* Wm = (const float*)d_in[4];
  float* out = (float*)d_out;

  char* ws = (char*)d_ws;
  // layout: Q' f32 | K f32 | xnb bf16 (dead after k_tr; hr overlays it) |
  //         xnt bf16 [64bh][64e][2048t] pre-swizzled | Wvmt bf16
  float*  Qp   = (float*)(ws);
  float*  Kp   = (float*)(ws + 524288);
  ushort* xnb  = (ushort*)(ws + 1048576);
  ushort* hrp  = (ushort*)(ws + 1048576);   // overlays xnb (dead after k_tr)
  ushort* xnt  = (ushort*)(ws + 17825792);
  ushort* Wvmt = (ushort*)(ws + 34603008);

  k_ln<<<4096, 256, 0, stream>>>(x, Wq, Wk, Qp, Kp, xnb);
  k_tr<<<dim3(TT / 64, 8 * NH), 256, 0, stream>>>(xnb, xnt);
  k_wvm<<<EE, 256, 0, stream>>>(Wv, Wm, Wvmt);
  k_attn<<<512, 256, 0, stream>>>(Qp, Kp, xnt, hrp);
  k_merge<<<dim3(EE / 128, (8 * TT) / 128), 256, 0, stream>>>(hrp, Wvmt, x, out);
}

// Round 11
// 119.160 us; speedup vs baseline: 1.5935x; 1.1942x over previous
//
#include <hip/hip_runtime.h>

typedef __bf16 bf16x8 __attribute__((ext_vector_type(8)));
typedef short short8 __attribute__((ext_vector_type(8)));
typedef float f32x4 __attribute__((ext_vector_type(4)));

// B=8, T=2048, E=512, H=8, d=64
#define TT 2048
#define EE 512
#define NH 8
#define DD 64

#define QSCALE 0.36067376022224085f   // 0.25 * log2(e)
#define CSCALE 0.18033688011112042f   // 0.125 * log2(e)

__device__ __forceinline__ ushort f2bf(float f) {
  union { float f; unsigned u; } a; a.f = f;
  unsigned u = a.u;
  return (ushort)((u + 0x7FFFu + ((u >> 16) & 1u)) >> 16);  // RNE
}

// ---------------- Kernel 1: fused LayerNorm + Q,K + transposed xnt ---------
// 1024 threads = 16 waves; block = 64 consecutive tokens (same batch b).
// Phase 1: wave-per-token LN (4 tokens/wave) -> LDS tile [64t][512e] bf16,
//          plus Q'/K head scalars.
// Phase 2: transposed, PRE-SWIZZLED writes to xnt[bh][e][t]:
//          8-t chunk c of row e stored at chunk (c ^ (e&7)) within each
//          64-t window (must match k_attn's vf read swizzle).
__global__ __launch_bounds__(1024) void k_lnt(
    const float* __restrict__ x, const float* __restrict__ Wq,
    const float* __restrict__ Wk,
    float* __restrict__ Q, float* __restrict__ K, ushort* __restrict__ xnt) {
  const int tid = threadIdx.x;
  const int wv = tid >> 6, l = tid & 63;
  const int t0 = blockIdx.x * 64;              // 2048 % 64 == 0 -> same b
  __shared__ ushort tile[64][520];             // 66,560 B

#pragma unroll
  for (int it = 0; it < 4; it++) {
    const int tl = wv * 4 + it;
    const int token = t0 + tl;
    const float* xr = x + (size_t)token * EE + l * 8;
    float4 a = *(const float4*)xr;
    float4 c = *(const float4*)(xr + 4);
    float xv[8] = {a.x, a.y, a.z, a.w, c.x, c.y, c.z, c.w};
    float s = 0.f, s2 = 0.f;
#pragma unroll
    for (int i = 0; i < 8; i++) { s += xv[i]; s2 = fmaf(xv[i], xv[i], s2); }
#pragma unroll
    for (int o = 32; o; o >>= 1) { s += __shfl_xor(s, o); s2 += __shfl_xor(s2, o); }
    const float mean = s * (1.f / 512.f);
    const float var = s2 * (1.f / 512.f) - mean * mean;
    const float rstd = rsqrtf(var + 1e-5f);

    float xn[8];
    short8 ob;
#pragma unroll
    for (int i = 0; i < 8; i++) {
      xn[i] = (xv[i] - mean) * rstd;
      ob[i] = (short)f2bf(xn[i]);
    }
    *(short8*)&tile[tl][l * 8] = ob;

    const float* wq = Wq + l * 8;
    const float* wk = Wk + l * 8;
    float4 q1 = *(const float4*)wq, q2 = *(const float4*)(wq + 4);
    float4 k1 = *(const float4*)wk, k2 = *(const float4*)(wk + 4);
    float wqv[8] = {q1.x, q1.y, q1.z, q1.w, q2.x, q2.y, q2.z, q2.w};
    float wkv[8] = {k1.x, k1.y, k1.z, k1.w, k2.x, k2.y, k2.z, k2.w};
    float q = 0.f, k = 0.f;
#pragma unroll
    for (int i = 0; i < 8; i++) { q = fmaf(xn[i], wqv[i], q); k = fmaf(xn[i], wkv[i], k); }
#pragma unroll
    for (int o = 4; o; o >>= 1) { q += __shfl_xor(q, o); k += __shfl_xor(k, o); }
    if ((l & 7) == 0) {
      const int h = l >> 3;
      const int b = token >> 11, t = token & (TT - 1);
      const int bh = b * NH + h;
      Q[bh * TT + t] = q * QSCALE;
      K[bh * TT + t] = k;
    }
  }
  __syncthreads();

  // phase 2: thread -> (h, e, half); gather column, swizzled uint4 stores
  {
    const int h = tid >> 7, e = (tid >> 1) & 63, half = tid & 1;
    const int b = t0 >> 11, trow = t0 & (TT - 1);
    const int col = h * 64 + e;
    ushort* rowp = xnt + (size_t)((b * NH + h) * DD + e) * TT + trow;
#pragma unroll
    for (int ch = 0; ch < 4; ch++) {
      const int c_idx = half * 4 + ch;
      union { uint4 v; ushort u[8]; } o;
#pragma unroll
      for (int i = 0; i < 8; i++) o.u[i] = tile[c_idx * 8 + i][col];
      *(uint4*)(rowp + (((c_idx ^ (e & 7)) << 3))) = o.v;
    }
  }
}

// ---------------- Kernel 2: Wvmt[n][k] = (Wv_h @ Wm_h)^T, bf16 -------------
// block per k (512 blocks); Wm rows read coalesced across 256 threads
__global__ __launch_bounds__(256) void k_wvm(
    const float* __restrict__ Wv, const float* __restrict__ Wm,
    ushort* __restrict__ Wvmt) {
  const int k = blockIdx.x;
  const int h = k >> 6;
  const int tid = threadIdx.x;
  __shared__ float wv[64];
  if (tid < 64) wv[tid] = Wv[k * 64 + tid];
  __syncthreads();
  float a0 = 0.f, a1 = 0.f;
#pragma unroll 8
  for (int e = 0; e < 64; e++) {
    const float w = wv[e];
    const float* row = Wm + (size_t)(h * 64 + e) * EE;
    a0 = fmaf(w, row[tid], a0);
    a1 = fmaf(w, row[tid + 256], a1);
  }
  Wvmt[(size_t)tid * EE + k] = f2bf(a0);
  Wvmt[(size_t)(tid + 256) * EE + k] = f2bf(a1);
}

// ---------------- Kernel 3: distance attention (R7 structure, verbatim) ----
// grid = 512 (XCD-swizzled); 256 threads = 4 waves; F=4 (64 q-rows/wave)
// pre-swizzled xnt -> linear b128 ds_write, swizzled b128 vf read,
// issue-early/write-late, ONE barrier per 64-j tile.
__global__ __launch_bounds__(256, 2) void k_attn(
    const float* __restrict__ Q, const float* __restrict__ K,
    const ushort* __restrict__ xnt, ushort* __restrict__ hr) {
  const int sw = (blockIdx.x & 7) * 64 + (blockIdx.x >> 3);  // bijective XCD swizzle
  const int bh = sw >> 3;
  const int q0 = (sw & 7) * 256;
  const int b = bh >> 3, h = bh & 7;
  const int tid = threadIdx.x;
  const int w = tid >> 6, l = tid & 63;
  const int l16 = l & 15, lhi = l >> 4;

  __shared__ float ks[TT];
  __shared__ float cs[TT];
  __shared__ ushort vt[2][64 * 64];

  // stage K row + score constants (one-time)
  {
    const float* Kb = K + bh * TT;
#pragma unroll
    for (int i = 0; i < 8; i++) {
      float kv = Kb[tid + i * 256];
      ks[tid + i * 256] = kv;
      cs[tid + i * 256] = -kv * kv * CSCALE;
    }
  }

  // staging geometry: lane -> rows e = tid>>3 and +32, chunk tid&7 (16B)
  const ushort* Xs = xnt + (size_t)bh * (DD * TT);
  const int se = tid >> 3;           // 0..31
  const int sc = (tid & 7) * 8;      // ushort offset within 64-j row
  uint4 st0, st1;

#define ISSUE_STAGE(jt_) do {                                                  \
    st0 = *(const uint4*)(Xs + (size_t)se * TT + (jt_) + sc);                  \
    st1 = *(const uint4*)(Xs + (size_t)(se + 32) * TT + (jt_) + sc);           \
  } while (0)

#define WRITE_STAGE(buf_) do {                                                 \
    *(uint4*)&vt[buf_][se * 64 + sc] = st0;                                    \
    *(uint4*)&vt[buf_][(se + 32) * 64 + sc] = st1;                             \
  } while (0)

  ISSUE_STAGE(0);
  WRITE_STAGE(0);
  __syncthreads();

  float qv[4];
#pragma unroll
  for (int f = 0; f < 4; f++) qv[f] = Q[bh * TT + q0 + w * 64 + f * 16 + l16];

  f32x4 acc[4][4];
  f32x4 accd[4];
#pragma unroll
  for (int f = 0; f < 4; f++) {
    accd[f] = (f32x4){0.f, 0.f, 0.f, 0.f};
#pragma unroll
    for (int c = 0; c < 4; c++) acc[f][c] = (f32x4){0.f, 0.f, 0.f, 0.f};
  }
  short8 onesbits = {0x3F80, 0x3F80, 0x3F80, 0x3F80, 0x3F80, 0x3F80, 0x3F80, 0x3F80};
  const bf16x8 ones = __builtin_bit_cast(bf16x8, onesbits);

  int p = 0;
  for (int jt = 0; jt < TT; jt += 64) {
    const bool more = (jt + 64) < TT;
    if (more) ISSUE_STAGE(jt + 64);   // issue-early: latency hides under compute

    __builtin_amdgcn_s_setprio(1);
#pragma unroll
    for (int kk = 0; kk < 2; kk++) {
      // B fragments: e = c*16+l16, chunk = (kk*4+lhi) ^ (e&7)  (pre-swizzled)
      bf16x8 vf[4];
#pragma unroll
      for (int c = 0; c < 4; c++) {
        const int e = c * 16 + l16;
        vf[c] = *(const bf16x8*)&vt[p][e * 64 + (((kk * 4 + lhi) ^ (e & 7)) << 3)];
      }
      const int jb = jt + kk * 32 + lhi * 8;
      float4 ka = *(const float4*)&ks[jb];
      float4 kb2 = *(const float4*)&ks[jb + 4];
      float4 ca = *(const float4*)&cs[jb];
      float4 cb2 = *(const float4*)&cs[jb + 4];
      float kv8[8] = {ka.x, ka.y, ka.z, ka.w, kb2.x, kb2.y, kb2.z, kb2.w};
      float cv8[8] = {ca.x, ca.y, ca.z, ca.w, cb2.x, cb2.y, cb2.z, cb2.w};
#pragma unroll
      for (int f = 0; f < 4; f++) {
        bf16x8 pa;
#pragma unroll
        for (int i = 0; i < 8; i++)
          pa[i] = (__bf16)__builtin_amdgcn_exp2f(fmaf(qv[f], kv8[i], cv8[i]));
        accd[f] = __builtin_amdgcn_mfma_f32_16x16x32_bf16(pa, ones, accd[f], 0, 0, 0);
#pragma unroll
        for (int c = 0; c < 4; c++)
          acc[f][c] = __builtin_amdgcn_mfma_f32_16x16x32_bf16(pa, vf[c], acc[f][c], 0, 0, 0);
      }
    }
    __builtin_amdgcn_s_setprio(0);

    if (more) WRITE_STAGE(p ^ 1);     // write-late: after compute, before barrier
    __syncthreads();
    p ^= 1;
  }
#undef ISSUE_STAGE
#undef WRITE_STAGE

#pragma unroll
  for (int f = 0; f < 4; f++) {
#pragma unroll
    for (int r = 0; r < 4; r++) {
      // C/D layout: row = lhi*4 + r, col = l16; accd row-sum is col-invariant
      const float rinv = 1.f / accd[f][r];
      const int qrow = q0 + w * 64 + f * 16 + lhi * 4 + r;
      const size_t base = ((size_t)(b * TT + qrow)) * EE + h * DD + l16;
#pragma unroll
      for (int c = 0; c < 4; c++)
        hr[base + c * 16] = f2bf(acc[f][c][r] * rinv);
    }
  }
}

// ---------------- Kernel 4: out = hr @ Wvm + x  (bf16 MFMA GEMM) -----------
// grid = (4, 128); 256 threads (4 waves, 2x2 wave grid, 64x64 each)
// R7 body + XCD-grouped remap: each XCD owns 16 m-strips x all 4 n-tiles,
// n fastest in dispatch order -> x/hr strips are L2 hits after first block.
__global__ __launch_bounds__(256, 2) void k_merge(
    const ushort* __restrict__ hr, const ushort* __restrict__ Wmt,
    const float* __restrict__ x, float* __restrict__ out) {
  const int fid = blockIdx.y * 4 + blockIdx.x;   // dispatch order (x fastest)
  const int xcd = fid & 7, idx = fid >> 3;
  const int n0 = (idx & 3) * 128;
  const int m0 = (xcd * 16 + (idx >> 2)) * 128;
  const int tid = threadIdx.x;
  const int w = tid >> 6, l = tid & 63;
  const int l16 = l & 15, lhi = l >> 4;
  const int wm = w >> 1, wn = w & 1;

  __shared__ ushort As[2][128 * 72];
  __shared__ ushort Bs[2][128 * 72];
  f32x4 acc[4][4];
#pragma unroll
  for (int i = 0; i < 4; i++)
#pragma unroll
    for (int j = 0; j < 4; j++) acc[i][j] = (f32x4){0.f, 0.f, 0.f, 0.f};

  const int row = tid >> 1, half = tid & 1;
  const ushort* sa0 = hr + (size_t)(m0 + row) * EE + half * 32;
  const ushort* sb0 = Wmt + (size_t)(n0 + row) * EE + half * 32;

  // prologue: stage k-step 0
  {
    uint4* da = (uint4*)&As[0][row * 72 + half * 32];
    uint4* db = (uint4*)&Bs[0][row * 72 + half * 32];
#pragma unroll
    for (int i = 0; i < 4; i++) da[i] = *(const uint4*)(sa0 + i * 8);
#pragma unroll
    for (int i = 0; i < 4; i++) db[i] = *(const uint4*)(sb0 + i * 8);
  }
  __syncthreads();

  int p = 0;
  for (int k0 = 0; k0 < EE; k0 += 64) {
    const bool more = (k0 + 64) < EE;
    uint4 pa[4], pb[4];
    if (more) {
#pragma unroll
      for (int i = 0; i < 4; i++) pa[i] = *(const uint4*)(sa0 + k0 + 64 + i * 8);
#pragma unroll
      for (int i = 0; i < 4; i++) pb[i] = *(const uint4*)(sb0 + k0 + 64 + i * 8);
    }
#pragma unroll
    for (int kk = 0; kk < 2; kk++) {
      bf16x8 af[4], bfr[4];
#pragma unroll
      for (int mi = 0; mi < 4; mi++)
        af[mi] = *(const bf16x8*)&As[p][(wm * 64 + mi * 16 + l16) * 72 + kk * 32 + lhi * 8];
#pragma unroll
      for (int ni = 0; ni < 4; ni++)
        bfr[ni] = *(const bf16x8*)&Bs[p][(wn * 64 + ni * 16 + l16) * 72 + kk * 32 + lhi * 8];
#pragma unroll
      for (int mi = 0; mi < 4; mi++)
#pragma unroll
        for (int ni = 0; ni < 4; ni++)
          acc[mi][ni] = __builtin_amdgcn_mfma_f32_16x16x32_bf16(af[mi], bfr[ni], acc[mi][ni], 0, 0, 0);
    }
    if (more) {
      uint4* da = (uint4*)&As[p ^ 1][row * 72 + half * 32];
      uint4* db = (uint4*)&Bs[p ^ 1][row * 72 + half * 32];
#pragma unroll
      for (int i = 0; i < 4; i++) da[i] = pa[i];
#pragma unroll
      for (int i = 0; i < 4; i++) db[i] = pb[i];
    }
    __syncthreads();
    p ^= 1;
  }

#pragma unroll
  for (int mi = 0; mi < 4; mi++) {
#pragma unroll
    for (int r = 0; r < 4; r++) {
      const int grow = m0 + wm * 64 + mi * 16 + lhi * 4 + r;
#pragma unroll
      for (int ni = 0; ni < 4; ni++) {
        const int gcol = n0 + wn * 64 + ni * 16 + l16;
        size_t idx2 = (size_t)grow * EE + gcol;
        out[idx2] = acc[mi][ni][r] + x[idx2];
      }
    }
  }
}

// ---------------- launch ----------------------------------------------------
extern "C" void kernel_launch(void* const* d_in, const int* in_sizes, int n_in,
                              void* d_out, int out_size, void* d_ws, size_t ws_size,
                              hipStream_t stream) {
  const float* x  = (const float*)d_in[0];
  const float* Wq = (const float*)d_in[1];
  const float* Wk = (const float*)d_in[2];
  const float* Wv = (const float*)d_in[3];
  const float* Wm = (const float*)d_in[4];
  float* out = (float*)d_out;

  char* ws = (char*)d_ws;
  // layout: Q' f32 | K f32 | hr bf16 [16384][512] |
  //         xnt bf16 [64bh][64e][2048t] pre-swizzled | Wvmt bf16
  float*  Qp   = (float*)(ws);
  float*  Kp   = (float*)(ws + 524288);
  ushort* hrp  = (ushort*)(ws + 1048576);
  ushort* xnt  = (ushort*)(ws + 17825792);
  ushort* Wvmt = (ushort*)(ws + 34603008);

  k_lnt<<<256, 1024, 0, stream>>>(x, Wq, Wk, Qp, Kp, xnt);
  k_wvm<<<EE, 256, 0, stream>>>(Wv, Wm, Wvmt);
  k_attn<<<512, 256, 0, stream>>>(Qp, Kp, xnt, hrp);
  k_merge<<<dim3(EE / 128, (8 * TT) / 128), 256, 0, stream>>>(hrp, Wvmt, x, out);
}